// Round 2
// baseline (376.474 us; speedup 1.0000x reference)
//
#include <hip/hip_runtime.h>
#include <math.h>

// Problem constants
#define A_     32
#define B_     32
#define KK_    9
#define KKA_   288     // KK*A
#define PSIZE_ 16
#define X_     512     // b*l = 8*64
#define F_     512     // B*PSIZE

// ---------------------------------------------------------------------------
// K1: fused unfold + capsule-vote + K/V projection + Gaussian-loglik softmax
//     (online, over n) + attention-weighted V sum.  One block per sample x.
//     thread t -> (o = t>>4, u = t&15); u = h*4+d.
// ---------------------------------------------------------------------------
__global__ __launch_bounds__(512) void k1_attn(
    const float* __restrict__ Xin,   // (8, 512, 17, 17)
    const float* __restrict__ Wc,    // (288, 32, 4, 4)
    const float* __restrict__ M,     // (1, 32, 16)
    const float* __restrict__ S,     // (1, 32, 16)
    const float* __restrict__ Wk,    // (16, 16)
    const float* __restrict__ bk,    // (16)
    const float* __restrict__ Wv,    // (16, 16)
    const float* __restrict__ bv,    // (16)
    float* __restrict__ Opre)        // (512, 512)  pre-BN0 output
{
    __shared__ float pose[KKA_][PSIZE_];   // 18 KiB

    const int x   = blockIdx.x;
    const int bi  = x >> 6;          // batch
    const int w   = x & 63;          // spatial
    const int ohi = w >> 3, owi = w & 7;
    const int tid = threadIdx.x;

    // ---- stage pose[x] into LDS ----
    // pose[n=kk*32+a][p] = X[bi, a*16+p, 2*ohi+ki, 2*owi+kj],  kk = ki*3+kj
    for (int idx = tid; idx < KKA_ * PSIZE_; idx += 512) {
        int n  = idx >> 4, p = idx & 15;
        int kk = n >> 5,  a = n & 31;
        int ki = kk / 3,  kj = kk - ki * 3;
        int ch = a * 16 + p;
        int r  = 2 * ohi + ki, c = 2 * owi + kj;
        pose[n][p] = Xin[((bi * 512 + ch) * 17 + r) * 17 + c];
    }

    const int o = tid >> 4;          // capsule 0..31
    const int u = tid & 15;          // dim 0..15 (= h*4+d)

    // per-thread constants
    float wk[16], wv[16];
#pragma unroll
    for (int j = 0; j < 16; ++j) { wk[j] = Wk[u * 16 + j]; wv[j] = Wv[u * 16 + j]; }
    const float bku = bk[u], bvu = bv[u];
    const float muu = M[o * 16 + u];
    const float sv  = S[o * 16 + u];
    const float sig = (sv > 20.f) ? sv : log1pf(__expf(sv));  // softplus
    const float rsig = 1.0f / sig;

    __syncthreads();

    // ---- online softmax over n ----
    // softmax input (constants in n cancel): llh = -0.125 * sum_d ((K-mu)/sig)^2
    float m = -1e30f, s = 0.f, acc = 0.f;
    const int   iu  = (u >> 2) * 4;   // pose row base (i*4)
    const int   kcol = u & 3;         // W_caps column k

    for (int n = 0; n < KKA_; ++n) {
        // vote: v_{i,k} = sum_j pose[n][i*4+j] * Wc[n][o][j][k]
        const float* wcn = Wc + ((n * 32 + o) * 16) + kcol;
        float v = 0.f;
#pragma unroll
        for (int j = 0; j < 4; ++j)
            v += pose[n][iu + j] * wcn[j * 4];

        // K/V projection: share the 16 v's across the capsule's 16 lanes
        float kt = bku, vt = bvu;
#pragma unroll
        for (int j = 0; j < 16; ++j) {
            float vj = __shfl(v, j, 16);
            kt += wk[j] * vj;
            vt += wv[j] * vj;
        }

        // Gaussian log-lik (n-varying part), reduced over the 4 ds lanes
        float z = (kt - muu) * rsig;
        float t = z * z;
        t += __shfl_xor(t, 1);
        t += __shfl_xor(t, 2);
        float llh = -0.125f * t;      // (-0.5 z^2 sum) / sqrt(dim)=4

        // online softmax update (m,s replicated across the 4 ds lanes)
        float mn    = fmaxf(m, llh);
        float scale = __expf(m - mn);
        float p     = __expf(llh - mn);
        s   = s * scale + p;
        acc = acc * scale + p * vt;
        m   = mn;
    }

    Opre[x * F_ + tid] = muu + acc / s;
}

// ---------------------------------------------------------------------------
// BN stats: per-feature mean & rstd over the 512 samples.
// grid 32 blocks x 256 threads; block handles 16 features.
// ---------------------------------------------------------------------------
__global__ __launch_bounds__(256) void k_stats(
    const float* __restrict__ Z,     // (512, 512)
    float* __restrict__ meanv,       // (512)
    float* __restrict__ rstdv)       // (512)
{
    __shared__ float ssum[256], ssq[256];
    const int tid = threadIdx.x;
    const int f   = blockIdx.x * 16 + (tid & 15);
    const int xg  = tid >> 4;

    float sum = 0.f, sq = 0.f;
    for (int x = xg; x < X_; x += 16) {
        float v = Z[x * F_ + f];
        sum += v; sq += v * v;
    }
    ssum[tid] = sum; ssq[tid] = sq;
    __syncthreads();
    for (int st = 128; st >= 16; st >>= 1) {
        if (tid < st) { ssum[tid] += ssum[tid + st]; ssq[tid] += ssq[tid + st]; }
        __syncthreads();
    }
    if (tid < 16) {
        float mean = ssum[tid] * (1.0f / X_);
        float var  = ssq[tid] * (1.0f / X_) - mean * mean;
        meanv[f] = mean;
        rstdv[f] = rsqrtf(var + 1e-5f);
    }
}

// ---------------------------------------------------------------------------
// K3: apply BN0, per-capsule 16x16 Wo matmul + relu residual.
// block per x, 512 threads (thread = feature f).
// ---------------------------------------------------------------------------
__global__ __launch_bounds__(512) void k_bn0_wo(
    const float* __restrict__ Opre,
    const float* __restrict__ mean0, const float* __restrict__ rstd0,
    const float* __restrict__ g0,    const float* __restrict__ beta0,
    const float* __restrict__ Wo,    const float* __restrict__ bo,
    float* __restrict__ O2)
{
    const int x = blockIdx.x, f = threadIdx.x;
    const int u = f & 15;

    float o1 = g0[f] * (Opre[x * F_ + f] - mean0[f]) * rstd0[f] + beta0[f];

    float wo[16];
#pragma unroll
    for (int j = 0; j < 16; ++j) wo[j] = Wo[u * 16 + j];

    float accv = bo[u];
#pragma unroll
    for (int j = 0; j < 16; ++j) {
        float oj = __shfl(o1, j, 16);   // 16-lane group == one capsule
        accv += wo[j] * oj;
    }
    O2[x * F_ + f] = o1 + fmaxf(accv, 0.f);
}

// ---------------------------------------------------------------------------
// K5: apply BN1 and write NCHW-transposed output.
// out[bi, f, ohi, owi] = bn1(O2)[x = bi*64 + ohi*8 + owi, f]
// ---------------------------------------------------------------------------
__global__ __launch_bounds__(256) void k_bn1_out(
    const float* __restrict__ O2,
    const float* __restrict__ mean1, const float* __restrict__ rstd1,
    const float* __restrict__ g1,    const float* __restrict__ beta1,
    float* __restrict__ out)
{
    const int idx = blockIdx.x * 256 + threadIdx.x;   // 262144 total
    const int w  = idx & 63;
    const int f  = (idx >> 6) & 511;
    const int bi = idx >> 15;
    const int x  = bi * 64 + w;
    out[idx] = g1[f] * (O2[x * F_ + f] - mean1[f]) * rstd1[f] + beta1[f];
}

// ---------------------------------------------------------------------------
extern "C" void kernel_launch(void* const* d_in, const int* in_sizes, int n_in,
                              void* d_out, int out_size, void* d_ws, size_t ws_size,
                              hipStream_t stream)
{
    const float* Xin = (const float*)d_in[0];
    const float* Wc  = (const float*)d_in[1];
    const float* M   = (const float*)d_in[2];
    const float* S   = (const float*)d_in[3];
    // d_in[4] = p_logit: cancels inside the softmax over n — unused.
    const float* Wk  = (const float*)d_in[5];
    const float* bk  = (const float*)d_in[6];
    const float* Wv  = (const float*)d_in[7];
    const float* bv  = (const float*)d_in[8];
    const float* Wo  = (const float*)d_in[9];
    const float* bo  = (const float*)d_in[10];
    const float* g0  = (const float*)d_in[11];
    const float* b0  = (const float*)d_in[12];
    const float* g1  = (const float*)d_in[13];
    const float* b1  = (const float*)d_in[14];

    float* out  = (float*)d_out;
    float* ws   = (float*)d_ws;
    float* Opre = ws;                       // 512*512
    float* O2   = ws + 262144;              // 512*512
    float* mean0 = ws + 524288;             // 512
    float* rstd0 = mean0 + 512;
    float* mean1 = rstd0 + 512;
    float* rstd1 = mean1 + 512;

    k1_attn <<<512, 512, 0, stream>>>(Xin, Wc, M, S, Wk, bk, Wv, bv, Opre);
    k_stats <<<32, 256, 0, stream>>>(Opre, mean0, rstd0);
    k_bn0_wo<<<512, 512, 0, stream>>>(Opre, mean0, rstd0, g0, b0, Wo, bo, O2);
    k_stats <<<32, 256, 0, stream>>>(O2, mean1, rstd1);
    k_bn1_out<<<1024, 256, 0, stream>>>(O2, mean1, rstd1, g1, b1, out);
}

// Round 4
// 243.303 us; speedup vs baseline: 1.5473x; 1.5473x over previous
//
#include <hip/hip_runtime.h>
#include <math.h>

// Problem constants
#define A_     32
#define B_     32
#define KK_    9
#define KKA_   288     // KK*A
#define PSIZE_ 16
#define X_     512     // b*l = 8*64
#define F_     512     // B*PSIZE

// ds_swizzle xor-patterns (BitMode: offset = (xor<<10)|(or<<5)|and, and=0x1F)
#define SWZ_XOR1 0x041F
#define SWZ_XOR2 0x081F

__device__ __forceinline__ float swz_xor(float t, int pat01) {
    // pat01: 1 -> xor1, 2 -> xor2 (compile-time)
    int r;
    if (pat01 == 1) r = __builtin_amdgcn_ds_swizzle(__float_as_int(t), SWZ_XOR1);
    else            r = __builtin_amdgcn_ds_swizzle(__float_as_int(t), SWZ_XOR2);
    return __int_as_float(r);
}

// ---------------------------------------------------------------------------
// K1: fused unfold + capsule-vote + K/V projection + Gaussian-loglik softmax
//     (online, over n) + attention-weighted V sum + BN0-stat accumulation.
//     One block per sample x. thread t -> (o = t>>4, u = t&15); u = h*4+d.
// ---------------------------------------------------------------------------
__global__ __launch_bounds__(512) void k1_attn(
    const float* __restrict__ Xin,   // (8, 512, 17, 17)
    const float* __restrict__ Wc,    // (288, 32, 4, 4)
    const float* __restrict__ M,     // (1, 32, 16)
    const float* __restrict__ S,     // (1, 32, 16)
    const float* __restrict__ Wk,    // (16, 16)
    const float* __restrict__ bk,    // (16)
    const float* __restrict__ Wv,    // (16, 16)
    const float* __restrict__ bv,    // (16)
    float* __restrict__ Opre,        // (512, 512)  pre-BN0 output
    float* __restrict__ fsum0,       // (512) BN0 sums   (pre-zeroed)
    float* __restrict__ fsq0)        // (512) BN0 sumsq  (pre-zeroed)
{
    __shared__ float pose[KKA_][PSIZE_];      // 18 KiB
    __shared__ float vbuf[8][4][PSIZE_];      // 2 KiB: [wave][o-group][u]

    const int x   = blockIdx.x;
    const int bi  = x >> 6;          // batch
    const int w   = x & 63;          // spatial
    const int ohi = w >> 3, owi = w & 7;
    const int tid = threadIdx.x;

    // ---- stage pose[x] into LDS ----
    for (int idx = tid; idx < KKA_ * PSIZE_; idx += 512) {
        int n  = idx >> 4, p = idx & 15;
        int kk = n >> 5,  a = n & 31;
        int ki = kk / 3,  kj = kk - ki * 3;
        int ch = a * 16 + p;
        int r  = 2 * ohi + ki, c = 2 * owi + kj;
        pose[n][p] = Xin[((bi * 512 + ch) * 17 + r) * 17 + c];
    }

    const int o   = tid >> 4;        // capsule 0..31
    const int u   = tid & 15;        // dim 0..15 (= h*4+d)
    const int wv_ = tid >> 6;        // wave 0..7
    const int og  = (tid >> 4) & 3;  // o-group within wave

    // per-thread constants
    float wk[16], wvv[16];
#pragma unroll
    for (int j = 0; j < 16; ++j) { wk[j] = Wk[u * 16 + j]; wvv[j] = Wv[u * 16 + j]; }
    const float bku = bk[u], bvu = bv[u];
    const float muu = M[o * 16 + u];
    const float sv  = S[o * 16 + u];
    const float sig = (sv > 20.f) ? sv : log1pf(__expf(sv));  // softplus
    const float rs  = 1.0f / sig;
    // fold: L = sum_d (kt-mu)^2 * rsig^2 * (-0.125*log2(e))   [exp2 domain]
    const float rs2C = rs * rs * -0.18033688011112042f;

    const int iu   = (u >> 2) * 4;   // pose row base (i*4)
    const int kcol = u & 3;          // W_caps column k

    // Wc prefetch pointer: element (n, o, j, kcol), n-stride = 512 floats
    const float* wcb = Wc + o * 16 + kcol;
    float c0 = wcb[0], c1 = wcb[4], c2 = wcb[8], c3 = wcb[12];  // n = 0

    __syncthreads();

    // ---- online softmax over n (exp2 domain) ----
    float m2 = -1e30f, s = 0.f, acc = 0.f;

#pragma unroll 2
    for (int n = 0; n < KKA_; ++n) {
        // prefetch Wc for n+1 (depth-1 pipeline)
        const float* wnx = wcb + ((n + 1 < KKA_) ? (n + 1) : 0) * 512;
        float n0 = wnx[0], n1 = wnx[4], n2 = wnx[8], n3 = wnx[12];

        // vote: v = pose[n][iu..iu+3] . Wc[n][o][:][kcol]
        const float4 pr = *(const float4*)&pose[n][iu];
        float v;
        v = pr.x * c0;
        v = fmaf(pr.y, c1, v);
        v = fmaf(pr.z, c2, v);
        v = fmaf(pr.w, c3, v);

        // broadcast the 16 v's of this capsule through LDS (in-wave, no barrier)
        vbuf[wv_][og][u] = v;
        const float4 va = *(const float4*)&vbuf[wv_][og][0];
        const float4 vb = *(const float4*)&vbuf[wv_][og][4];
        const float4 vc = *(const float4*)&vbuf[wv_][og][8];
        const float4 vd = *(const float4*)&vbuf[wv_][og][12];

        // K/V projection (16 j's each)
        float kt = bku, vt = bvu;
        kt = fmaf(wk[0],  va.x, kt); vt = fmaf(wvv[0],  va.x, vt);
        kt = fmaf(wk[1],  va.y, kt); vt = fmaf(wvv[1],  va.y, vt);
        kt = fmaf(wk[2],  va.z, kt); vt = fmaf(wvv[2],  va.z, vt);
        kt = fmaf(wk[3],  va.w, kt); vt = fmaf(wvv[3],  va.w, vt);
        kt = fmaf(wk[4],  vb.x, kt); vt = fmaf(wvv[4],  vb.x, vt);
        kt = fmaf(wk[5],  vb.y, kt); vt = fmaf(wvv[5],  vb.y, vt);
        kt = fmaf(wk[6],  vb.z, kt); vt = fmaf(wvv[6],  vb.z, vt);
        kt = fmaf(wk[7],  vb.w, kt); vt = fmaf(wvv[7],  vb.w, vt);
        kt = fmaf(wk[8],  vc.x, kt); vt = fmaf(wvv[8],  vc.x, vt);
        kt = fmaf(wk[9],  vc.y, kt); vt = fmaf(wvv[9],  vc.y, vt);
        kt = fmaf(wk[10], vc.z, kt); vt = fmaf(wvv[10], vc.z, vt);
        kt = fmaf(wk[11], vc.w, kt); vt = fmaf(wvv[11], vc.w, vt);
        kt = fmaf(wk[12], vd.x, kt); vt = fmaf(wvv[12], vd.x, vt);
        kt = fmaf(wk[13], vd.y, kt); vt = fmaf(wvv[13], vd.y, vt);
        kt = fmaf(wk[14], vd.z, kt); vt = fmaf(wvv[14], vd.z, vt);
        kt = fmaf(wk[15], vd.w, kt); vt = fmaf(wvv[15], vd.w, vt);

        // scaled log-lik (exp2 domain), reduced over the 4 ds lanes
        float diff = kt - muu;
        float tt = diff * diff * rs2C;          // per-lane scaled contribution
        tt += swz_xor(tt, 1);
        tt += swz_xor(tt, 2);                   // tt = L (uniform across d-group)

        // online softmax update
        float mn = fmaxf(m2, tt);
        float sc = exp2f(m2 - mn);
        float p  = exp2f(tt - mn);
        s   = fmaf(s, sc, p);
        acc = fmaf(acc, sc, p * vt);
        m2  = mn;

        c0 = n0; c1 = n1; c2 = n2; c3 = n3;
    }

    float res = muu + acc / s;
    Opre[x * F_ + tid] = res;
    atomicAdd(&fsum0[tid], res);
    atomicAdd(&fsq0[tid], res * res);
}

// ---------------------------------------------------------------------------
// K3: apply BN0 (stats from fsum0/fsq0), per-capsule 16x16 Wo matmul + relu
//     residual, and accumulate BN1 stats. Block per x, 512 threads.
// ---------------------------------------------------------------------------
__global__ __launch_bounds__(512) void k_bn0_wo(
    const float* __restrict__ Opre,
    const float* __restrict__ fsum0, const float* __restrict__ fsq0,
    const float* __restrict__ g0,    const float* __restrict__ beta0,
    const float* __restrict__ Wo,    const float* __restrict__ bo,
    float* __restrict__ O2,
    float* __restrict__ fsum1,       float* __restrict__ fsq1)
{
    __shared__ float sh[F_];
    const int x = blockIdx.x, f = threadIdx.x;
    const int u = f & 15, base = f & ~15;

    const float mean = fsum0[f] * (1.0f / X_);
    const float var  = fsq0[f] * (1.0f / X_) - mean * mean;
    const float rstd = rsqrtf(var + 1e-5f);

    float o1 = g0[f] * (Opre[x * F_ + f] - mean) * rstd + beta0[f];
    sh[f] = o1;
    __syncthreads();

    float accv = bo[u];
#pragma unroll
    for (int j = 0; j < 16; ++j)
        accv = fmaf(Wo[u * 16 + j], sh[base + j], accv);

    float r = o1 + fmaxf(accv, 0.f);
    O2[x * F_ + f] = r;
    atomicAdd(&fsum1[f], r);
    atomicAdd(&fsq1[f], r * r);
}

// ---------------------------------------------------------------------------
// K5: apply BN1 (stats from fsum1/fsq1) and write NCHW-transposed output.
// ---------------------------------------------------------------------------
__global__ __launch_bounds__(256) void k_bn1_out(
    const float* __restrict__ O2,
    const float* __restrict__ fsum1, const float* __restrict__ fsq1,
    const float* __restrict__ g1,    const float* __restrict__ beta1,
    float* __restrict__ out)
{
    const int idx = blockIdx.x * 256 + threadIdx.x;   // 262144 total
    const int w  = idx & 63;
    const int f  = (idx >> 6) & 511;
    const int bi = idx >> 15;
    const int x  = bi * 64 + w;

    const float mean = fsum1[f] * (1.0f / X_);
    const float var  = fsq1[f] * (1.0f / X_) - mean * mean;
    const float rstd = rsqrtf(var + 1e-5f);

    out[idx] = g1[f] * (O2[x * F_ + f] - mean) * rstd + beta1[f];
}

// ---------------------------------------------------------------------------
extern "C" void kernel_launch(void* const* d_in, const int* in_sizes, int n_in,
                              void* d_out, int out_size, void* d_ws, size_t ws_size,
                              hipStream_t stream)
{
    const float* Xin = (const float*)d_in[0];
    const float* Wc  = (const float*)d_in[1];
    const float* M   = (const float*)d_in[2];
    const float* S   = (const float*)d_in[3];
    // d_in[4] = p_logit: cancels inside the softmax over n — unused.
    const float* Wk  = (const float*)d_in[5];
    const float* bk  = (const float*)d_in[6];
    const float* Wv  = (const float*)d_in[7];
    const float* bv  = (const float*)d_in[8];
    const float* Wo  = (const float*)d_in[9];
    const float* bo  = (const float*)d_in[10];
    const float* g0  = (const float*)d_in[11];
    const float* b0  = (const float*)d_in[12];
    const float* g1  = (const float*)d_in[13];
    const float* b1  = (const float*)d_in[14];

    float* out   = (float*)d_out;
    float* ws    = (float*)d_ws;
    float* Opre  = ws;                      // 512*512
    float* O2    = ws + 262144;             // 512*512
    float* fsum0 = ws + 524288;             // 512
    float* fsq0  = fsum0 + 512;
    float* fsum1 = fsq0 + 512;
    float* fsq1  = fsum1 + 512;

    hipMemsetAsync(fsum0, 0, 4 * 512 * sizeof(float), stream);
    k1_attn <<<512, 512, 0, stream>>>(Xin, Wc, M, S, Wk, bk, Wv, bv,
                                      Opre, fsum0, fsq0);
    k_bn0_wo<<<512, 512, 0, stream>>>(Opre, fsum0, fsq0, g0, b0, Wo, bo,
                                      O2, fsum1, fsq1);
    k_bn1_out<<<1024, 256, 0, stream>>>(O2, fsum1, fsq1, g1, b1, out);
}

// Round 7
// 201.697 us; speedup vs baseline: 1.8665x; 1.2063x over previous
//
#include <hip/hip_runtime.h>
#include <math.h>

// Problem constants
#define KKA_ 288      // 9*32 routing positions
#define X_   512      // b*l
#define F_   512      // B*PSIZE

typedef _Float16 f16x4 __attribute__((ext_vector_type(4)));
typedef float    f32x4 __attribute__((ext_vector_type(4)));

// ---------------------------------------------------------------------------
// prep_wc: Wc16T[no*16 + k*4 + e] = (f16) Wc[no*16 + e*4 + k]
// so a lane (k) can load its A-fragment row as one contiguous f16x4.
// ---------------------------------------------------------------------------
__global__ __launch_bounds__(256) void prep_wc(const float* __restrict__ Wc,
                                               _Float16* __restrict__ Wc16T) {
    int idx = blockIdx.x * 256 + threadIdx.x;     // 288*32*16 = 147456
    if (idx >= KKA_ * 32 * 16) return;
    int no = idx >> 4, t = idx & 15;
    int k = t >> 2, e = t & 3;
    Wc16T[idx] = (_Float16)Wc[no * 16 + e * 4 + k];
}

// ---------------------------------------------------------------------------
// k1_mfma: grid = 32 x-tiles x 16 o-pairs = 512 blocks, 256 thr = 4 waves.
// wave wid: olocal = wid>>1, nh = wid&1.  o = ob*2+olocal, n in [nh*144, +144).
// Per n:  avf = Wc16T-frag * blockdiag-mask;  va = mfma(avf, pose^T);
//         in-lane cvt -> vf;  ck = mfma(Wk, vf, bk-mu); cv = mfma(Wv, vf, bv);
//         online softmax in-lane (lane=(x,h), regs=d).
// Epilogue: LDS merge of the two n-halves, Opre write + BN0 atomic stats.
// Layout verified in round 5 (first-pass absmax 0.0156).
// ---------------------------------------------------------------------------
__global__ __launch_bounds__(256) void k1_mfma(
    const float* __restrict__ Xin, const _Float16* __restrict__ Wc16T,
    const float* __restrict__ M,   const float* __restrict__ S,
    const float* __restrict__ Wk,  const float* __restrict__ bk,
    const float* __restrict__ Wv,  const float* __restrict__ bv,
    float* __restrict__ Opre, float* __restrict__ fsum0, float* __restrict__ fsq0)
{
    __shared__ __align__(16) _Float16 pose[72 * 256];   // [nl][xin][p]  36,864 B
    __shared__ float mbuf[2][64][6];                    // merge buffer   3,072 B

    const int bid = blockIdx.x;
    const int xt = bid >> 4, ob = bid & 15;
    const int x0 = xt * 16, bi = xt >> 2;
    const int tid = threadIdx.x;
    const int lane = tid & 63, wid = tid >> 6;
    const int l4 = lane >> 4, l15 = lane & 15;
    const int o  = ob * 2 + (wid >> 1);
    const int nh = wid & 1;

    // staging coords (thread = (p, xin), xin fastest for coalescing)
    const int sxin  = tid & 15;
    const int w     = (xt & 3) * 16 + sxin;
    const int rbase = 2 * (w >> 3), cbase = 2 * (w & 7);

    // per-thread constants
    f16x4 wkf, wvf;
#pragma unroll
    for (int e = 0; e < 4; ++e) {
        wkf[e] = (_Float16)Wk[l15 * 16 + l4 * 4 + e];
        wvf[e] = (_Float16)Wv[l15 * 16 + l4 * 4 + e];
    }
    f32x4 bvI, muI, wgt;
#pragma unroll
    for (int r = 0; r < 4; ++r) {
        int u = l4 * 4 + r;
        bvI[r] = bv[u];
        muI[r] = bk[u] - M[o * 16 + u];
        float sv = S[o * 16 + u];
        float sg = (sv > 20.f) ? sv : log1pf(__expf(sv));
        float rs = 1.f / sg;
        wgt[r] = rs * rs * -0.18033688011112042f;  // -0.125*log2e*rs^2
    }
    const _Float16 mk = ((l15 >> 2) == l4) ? (_Float16)1.f : (_Float16)0.f;
    const f16x4 mkv = {mk, mk, mk, mk};
    const _Float16* wcT = Wc16T + o * 16 + (lane & 3) * 4;   // + n*512

    float m2 = -1e30f, ss = 0.f;
    f32x4 accv = {0.f, 0.f, 0.f, 0.f};

    f16x4 q = *(const f16x4*)(wcT + (size_t)(nh * 144) * 512);   // prefetch n=first

    for (int r = 0; r < 4; ++r) {
        __syncthreads();
        // stage 72 n (36 per half) for round r
        for (int i = tid; i < 72 * 256; i += 256) {
            int rest = i >> 4;                 // i&15 == sxin (const per thread)
            int nl = rest % 72, p = rest / 72;
            int hf = (nl >= 36);
            int n  = hf * 144 + r * 36 + (nl - hf * 36);
            int kk = n >> 5, a = n & 31;
            int ki = kk / 3, kj = kk - ki * 3;
            pose[(nl * 16 + sxin) * 16 + p] =
                (_Float16)Xin[((bi * 512 + a * 16 + p) * 17 + rbase + ki) * 17 + cbase + kj];
        }
        __syncthreads();
        for (int nloc = 0; nloc < 36; ++nloc) {
            int tnext = r * 36 + nloc + 1;
            if (tnext > 143) tnext = 143;
            f16x4 qn = *(const f16x4*)(wcT + (size_t)(nh * 144 + tnext) * 512);

            f16x4 avf = q * mkv;   // block-diag mask
            f16x4 pfrag = *(const f16x4*)&pose[((nh * 36 + nloc) * 16 + l15) * 16 + l4 * 4];
            f32x4 va = __builtin_amdgcn_mfma_f32_16x16x16f16(
                avf, pfrag, (f32x4){0.f, 0.f, 0.f, 0.f}, 0, 0, 0);
            f16x4 vf;
#pragma unroll
            for (int e = 0; e < 4; ++e) vf[e] = (_Float16)va[e];
            f32x4 ck = __builtin_amdgcn_mfma_f32_16x16x16f16(wkf, vf, muI, 0, 0, 0);
            f32x4 cv = __builtin_amdgcn_mfma_f32_16x16x16f16(wvf, vf, bvI, 0, 0, 0);

            float tt =      ck[0] * ck[0] * wgt[0];
            tt = fmaf(ck[1] * ck[1], wgt[1], tt);
            tt = fmaf(ck[2] * ck[2], wgt[2], tt);
            tt = fmaf(ck[3] * ck[3], wgt[3], tt);

            float mn = fmaxf(m2, tt);
            float sc = exp2f(m2 - mn);
            float p  = exp2f(tt - mn);
            ss = fmaf(ss, sc, p);
#pragma unroll
            for (int rr = 0; rr < 4; ++rr) accv[rr] = fmaf(accv[rr], sc, p * cv[rr]);
            m2 = mn;
            q = qn;
        }
    }

    // ---- merge the two n-halves through LDS ----
    __syncthreads();
    if (nh == 1) {
        float* mb = mbuf[wid >> 1][lane];
        mb[0] = m2; mb[1] = ss;
        mb[2] = accv[0]; mb[3] = accv[1]; mb[4] = accv[2]; mb[5] = accv[3];
    }
    __syncthreads();
    if (nh == 0) {
        const float* mb = mbuf[wid >> 1][lane];
        float m1 = mb[0], s1 = mb[1];
        float mn = fmaxf(m2, m1);
        float sA = exp2f(m2 - mn), sB = exp2f(m1 - mn);
        float inv = 1.f / (ss * sA + s1 * sB);
        f32x4 res;
        float sums[4], sqs[4];
#pragma unroll
        for (int rr = 0; rr < 4; ++rr) {
            float a = accv[rr] * sA + mb[2 + rr] * sB;
            res[rr] = M[o * 16 + l4 * 4 + rr] + a * inv;
            sums[rr] = res[rr];
            sqs[rr]  = res[rr] * res[rr];
        }
        *(f32x4*)&Opre[(size_t)(x0 + l15) * F_ + o * 16 + l4 * 4] = res;
        // reduce BN0 stats over the 16 x in this block (l15 groups)
#pragma unroll
        for (int mm = 1; mm < 16; mm <<= 1) {
#pragma unroll
            for (int rr = 0; rr < 4; ++rr) {
                sums[rr] += __shfl_xor(sums[rr], mm, 16);
                sqs[rr]  += __shfl_xor(sqs[rr], mm, 16);
            }
        }
        if (l15 == 0) {
#pragma unroll
            for (int rr = 0; rr < 4; ++rr) {
                atomicAdd(&fsum0[o * 16 + l4 * 4 + rr], sums[rr]);
                atomicAdd(&fsq0[o * 16 + l4 * 4 + rr],  sqs[rr]);
            }
        }
    }
}

// ---------------------------------------------------------------------------
// k_bn0_wo: apply BN0, per-capsule 16x16 Wo + relu residual, BN1 stats.
// IN-PLACE on Opre (each thread reads/writes only its own element).
// ---------------------------------------------------------------------------
__global__ __launch_bounds__(512) void k_bn0_wo(
    float* __restrict__ Opre,
    const float* __restrict__ fsum0, const float* __restrict__ fsq0,
    const float* __restrict__ g0,    const float* __restrict__ beta0,
    const float* __restrict__ Wo,    const float* __restrict__ bo,
    float* __restrict__ fsum1,       float* __restrict__ fsq1)
{
    __shared__ float sh[F_];
    const int x = blockIdx.x, f = threadIdx.x;
    const int u = f & 15, base = f & ~15;

    const float mean = fsum0[f] * (1.0f / X_);
    const float var  = fsq0[f] * (1.0f / X_) - mean * mean;
    const float rstd = rsqrtf(var + 1e-5f);

    float o1 = g0[f] * (Opre[x * F_ + f] - mean) * rstd + beta0[f];
    sh[f] = o1;
    __syncthreads();

    float accv = bo[u];
#pragma unroll
    for (int j = 0; j < 16; ++j)
        accv = fmaf(Wo[u * 16 + j], sh[base + j], accv);

    float r = o1 + fmaxf(accv, 0.f);
    Opre[x * F_ + f] = r;
    atomicAdd(&fsum1[f], r);
    atomicAdd(&fsq1[f], r * r);
}

// ---------------------------------------------------------------------------
// k_bn1_out: apply BN1 and write NCHW-transposed output.
// ---------------------------------------------------------------------------
__global__ __launch_bounds__(256) void k_bn1_out(
    const float* __restrict__ O2,
    const float* __restrict__ fsum1, const float* __restrict__ fsq1,
    const float* __restrict__ g1,    const float* __restrict__ beta1,
    float* __restrict__ out)
{
    const int idx = blockIdx.x * 256 + threadIdx.x;   // 262144 total
    const int w  = idx & 63;
    const int f  = (idx >> 6) & 511;
    const int bi = idx >> 15;
    const int x  = bi * 64 + w;

    const float mean = fsum1[f] * (1.0f / X_);
    const float var  = fsq1[f] * (1.0f / X_) - mean * mean;
    const float rstd = rsqrtf(var + 1e-5f);

    out[idx] = g1[f] * (O2[x * F_ + f] - mean) * rstd + beta1[f];
}

// ---------------------------------------------------------------------------
extern "C" void kernel_launch(void* const* d_in, const int* in_sizes, int n_in,
                              void* d_out, int out_size, void* d_ws, size_t ws_size,
                              hipStream_t stream)
{
    const float* Xin = (const float*)d_in[0];
    const float* Wc  = (const float*)d_in[1];
    const float* M   = (const float*)d_in[2];
    const float* S   = (const float*)d_in[3];
    // d_in[4] = p_logit: constant in n, cancels in the softmax — unused.
    const float* Wk  = (const float*)d_in[5];
    const float* bk  = (const float*)d_in[6];
    const float* Wv  = (const float*)d_in[7];
    const float* bv  = (const float*)d_in[8];
    const float* Wo  = (const float*)d_in[9];
    const float* bo  = (const float*)d_in[10];
    const float* g0  = (const float*)d_in[11];
    const float* b0  = (const float*)d_in[12];
    const float* g1  = (const float*)d_in[13];
    const float* b1  = (const float*)d_in[14];
    float* out = (float*)d_out;

    // ---- workspace layout: 1.29 MB total (round-4 proved >= 2.1 MB safe) ----
    char* base = (char*)d_ws;
    _Float16* Wc16T = (_Float16*)base;                 // 294,912 B
    float* Opre  = (float*)(base + 294912);            // 1 MB
    float* fsum0 = Opre + 262144;                      // 4 x 512 stats
    float* fsq0  = fsum0 + 512;
    float* fsum1 = fsq0  + 512;
    float* fsq1  = fsum1 + 512;

    hipMemsetAsync(fsum0, 0, 4 * 512 * sizeof(float), stream);
    prep_wc <<<576, 256, 0, stream>>>(Wc, Wc16T);
    k1_mfma <<<512, 256, 0, stream>>>(Xin, Wc16T, M, S, Wk, bk, Wv, bv,
                                      Opre, fsum0, fsq0);
    k_bn0_wo<<<512, 512, 0, stream>>>(Opre, fsum0, fsq0, g0, b0, Wo, bo,
                                      fsum1, fsq1);
    k_bn1_out<<<1024, 256, 0, stream>>>(Opre, fsum1, fsq1, g1, b1, out);
}

// Round 10
// 143.653 us; speedup vs baseline: 2.6207x; 1.4041x over previous
//
#include <hip/hip_runtime.h>
#include <math.h>

// Problem constants
#define KKA_ 288      // 9*32 routing positions
#define X_   512      // b*l
#define F_   512      // B*PSIZE

typedef _Float16 f16x4 __attribute__((ext_vector_type(4)));
typedef float    f32x4 __attribute__((ext_vector_type(4)));

// ---------------------------------------------------------------------------
// prep: (a) blocks 0..575: Wc16T[no*16+k*4+e] = (f16) Wc[no*16+e*4+k]  (r7-proven)
//       (b) block 576: zero the 2048-float stats area.
// ---------------------------------------------------------------------------
__global__ __launch_bounds__(256) void prep(const float* __restrict__ Wc,
                                            _Float16* __restrict__ Wc16T,
                                            float* __restrict__ stats) {
    int b = blockIdx.x;
    if (b < 576) {
        int idx = b * 256 + threadIdx.x;          // exactly 147456
        int no = idx >> 4, t = idx & 15;
        int k = t >> 2, e = t & 3;
        Wc16T[idx] = (_Float16)Wc[no * 16 + e * 4 + k];
    } else {
        for (int i = threadIdx.x; i < 2048; i += 256) stats[i] = 0.f;
    }
}

// ---------------------------------------------------------------------------
// k1_mfma: grid = 1024 blocks = (xt 0..31, o 0..31), 256 thr = 4 waves.
// Wave wid owns n in [wid*72, +72).  No pose staging: lane (l15=x, l4) loads
// its 4 pose f32 straight from Xin (L2-resident) via per-n LDS offset table
// + immediate offsets, cvt to f16 in-lane.  MFMA datapath identical to the
// r5/r7-verified one.  Softmax WITHOUT max (tt<=0 -> exp2 in (0,1]); the 4
// wave-partials (s, acc4) are plain sums, merged through LDS by wave 0.
// sigma folded into Wk-fragment: ck = (kt-mu)*sqrt(0.1803)*rs -> tt=-sum ck^2.
// Writes OpreT[f][x] (transposed) + BN0 stat atomics.
// ---------------------------------------------------------------------------
__global__ __launch_bounds__(256, 4) void k1_mfma(
    const float* __restrict__ Xin, const _Float16* __restrict__ Wc16T,
    const float* __restrict__ M,   const float* __restrict__ S,
    const float* __restrict__ Wk,  const float* __restrict__ bk,
    const float* __restrict__ Wv,  const float* __restrict__ bv,
    float* __restrict__ OpreT, float* __restrict__ fsum0, float* __restrict__ fsq0)
{
    __shared__ int   tbl[KKA_];       // per-n Xin element offset (lane-invariant part)
    __shared__ float mbuf[3][64][6];  // wave-partial merge

    const int bid = blockIdx.x;
    const int swz = (bid & 7) * 128 + (bid >> 3);   // XCD-chunked, bijective (1024%8==0)
    const int xt = swz >> 5, o = swz & 31;
    const int tid = threadIdx.x;
    const int lane = tid & 63, wid = tid >> 6;
    const int l4 = lane >> 4, l15 = lane & 15;

    // offset table: n -> a*16*289 + ki*17 + kj   (elements)
    for (int i = tid; i < KKA_; i += 256) {
        int kk = i >> 5, a = i & 31;
        int ki = kk / 3, kj = kk - ki * 3;
        tbl[i] = a * 4624 + ki * 17 + kj;
    }

    const int x0 = xt * 16, bi = xt >> 2;
    const int w = (xt & 3) * 16 + l15;              // spatial pos of this lane's x
    const int rbase = 2 * (w >> 3), cbase = 2 * (w & 7);
    // lane-constant base: Xin[bi][ch = p-part][rbase][cbase], p = l4*4 (+e via imm)
    const float* xb = Xin + ((size_t)bi * 512 * 289 + (l4 * 4) * 289 + rbase * 17 + cbase);

    // Wk fragment scaled by sw(u=l15) = sqrt(0.125*log2e)*rs(l15)
    const float svl = S[o * 16 + l15];
    const float sgl = (svl > 20.f) ? svl : log1pf(__expf(svl));
    const float swl = 0.42466089f / sgl;            // sqrt(0.18033688)
    f16x4 wkf, wvf;
#pragma unroll
    for (int e = 0; e < 4; ++e) {
        wkf[e] = (_Float16)(Wk[l15 * 16 + l4 * 4 + e] * swl);
        wvf[e] = (_Float16)Wv[l15 * 16 + l4 * 4 + e];
    }
    f32x4 bvI, muI;
#pragma unroll
    for (int r = 0; r < 4; ++r) {
        int u = l4 * 4 + r;
        bvI[r] = bv[u];
        float sv = S[o * 16 + u];
        float sg = (sv > 20.f) ? sv : log1pf(__expf(sv));
        muI[r] = (bk[u] - M[o * 16 + u]) * (0.42466089f / sg);
    }
    const _Float16 mk = ((l15 >> 2) == l4) ? (_Float16)1.f : (_Float16)0.f;
    const f16x4 mkv = {mk, mk, mk, mk};
    const _Float16* wcT = Wc16T + o * 16 + (lane & 3) * 4;   // + n*512

    __syncthreads();

    const int n0 = wid * 72;
    // depth-2 prefetch: slot A = n0, slot B = n0+1
    const float* pA = xb + tbl[n0];
    float a0 = pA[0], a1 = pA[289], a2 = pA[578], a3 = pA[867];
    f16x4 qA = *(const f16x4*)(wcT + (size_t)n0 * 512);
    const float* pB = xb + tbl[n0 + 1];
    float b0 = pB[0], b1 = pB[289], b2 = pB[578], b3 = pB[867];
    f16x4 qB = *(const f16x4*)(wcT + (size_t)(n0 + 1) * 512);

    float ss = 0.f;
    f32x4 accv = {0.f, 0.f, 0.f, 0.f};

    for (int nl = 0; nl < 72; nl += 2) {
        {   // even iter: consume slot A, prefetch nl+2 -> A
            int np = (nl + 2 < 72) ? nl + 2 : 70;   // clamp: re-read, unused
            const float* pn = xb + tbl[n0 + np];
            float t0 = pn[0], t1 = pn[289], t2 = pn[578], t3 = pn[867];
            f16x4 qn = *(const f16x4*)(wcT + (size_t)(n0 + np) * 512);

            f16x4 pf; pf[0] = (_Float16)a0; pf[1] = (_Float16)a1;
                      pf[2] = (_Float16)a2; pf[3] = (_Float16)a3;
            f16x4 avf = qA * mkv;
            f32x4 va = __builtin_amdgcn_mfma_f32_16x16x16f16(
                avf, pf, (f32x4){0.f, 0.f, 0.f, 0.f}, 0, 0, 0);
            f16x4 vf;
#pragma unroll
            for (int e = 0; e < 4; ++e) vf[e] = (_Float16)va[e];
            f32x4 ck = __builtin_amdgcn_mfma_f32_16x16x16f16(wkf, vf, muI, 0, 0, 0);
            f32x4 cv = __builtin_amdgcn_mfma_f32_16x16x16f16(wvf, vf, bvI, 0, 0, 0);
            float tt = ck[0] * ck[0];
            tt = fmaf(ck[1], ck[1], tt);
            tt = fmaf(ck[2], ck[2], tt);
            tt = fmaf(ck[3], ck[3], tt);
            float p = exp2f(-tt);
            ss += p;
#pragma unroll
            for (int r = 0; r < 4; ++r) accv[r] = fmaf(p, cv[r], accv[r]);
            a0 = t0; a1 = t1; a2 = t2; a3 = t3; qA = qn;
        }
        {   // odd iter: consume slot B, prefetch nl+3 -> B
            int np = (nl + 3 < 72) ? nl + 3 : 71;
            const float* pn = xb + tbl[n0 + np];
            float t0 = pn[0], t1 = pn[289], t2 = pn[578], t3 = pn[867];
            f16x4 qn = *(const f16x4*)(wcT + (size_t)(n0 + np) * 512);

            f16x4 pf; pf[0] = (_Float16)b0; pf[1] = (_Float16)b1;
                      pf[2] = (_Float16)b2; pf[3] = (_Float16)b3;
            f16x4 avf = qB * mkv;
            f32x4 va = __builtin_amdgcn_mfma_f32_16x16x16f16(
                avf, pf, (f32x4){0.f, 0.f, 0.f, 0.f}, 0, 0, 0);
            f16x4 vf;
#pragma unroll
            for (int e = 0; e < 4; ++e) vf[e] = (_Float16)va[e];
            f32x4 ck = __builtin_amdgcn_mfma_f32_16x16x16f16(wkf, vf, muI, 0, 0, 0);
            f32x4 cv = __builtin_amdgcn_mfma_f32_16x16x16f16(wvf, vf, bvI, 0, 0, 0);
            float tt = ck[0] * ck[0];
            tt = fmaf(ck[1], ck[1], tt);
            tt = fmaf(ck[2], ck[2], tt);
            tt = fmaf(ck[3], ck[3], tt);
            float p = exp2f(-tt);
            ss += p;
#pragma unroll
            for (int r = 0; r < 4; ++r) accv[r] = fmaf(p, cv[r], accv[r]);
            b0 = t0; b1 = t1; b2 = t2; b3 = t3; qB = qn;
        }
    }

    // ---- sum-merge 4 wave partials (no max needed) ----
    __syncthreads();
    if (wid > 0) {
        float* mb = mbuf[wid - 1][lane];
        mb[0] = ss; mb[1] = accv[0]; mb[2] = accv[1]; mb[3] = accv[2]; mb[4] = accv[3];
    }
    __syncthreads();
    if (wid == 0) {
#pragma unroll
        for (int s2 = 0; s2 < 3; ++s2) {
            const float* mb = mbuf[s2][lane];
            ss += mb[0];
            accv[0] += mb[1]; accv[1] += mb[2]; accv[2] += mb[3]; accv[3] += mb[4];
        }
        float inv = 1.f / ss;
        float sums[4], sqs[4];
#pragma unroll
        for (int r = 0; r < 4; ++r) {
            float res = M[o * 16 + l4 * 4 + r] + accv[r] * inv;
            OpreT[(size_t)(o * 16 + l4 * 4 + r) * X_ + x0 + l15] = res;
            sums[r] = res; sqs[r] = res * res;
        }
#pragma unroll
        for (int mm = 1; mm < 16; mm <<= 1) {
#pragma unroll
            for (int r = 0; r < 4; ++r) {
                sums[r] += __shfl_xor(sums[r], mm, 16);
                sqs[r]  += __shfl_xor(sqs[r], mm, 16);
            }
        }
        if (l15 == 0) {
#pragma unroll
            for (int r = 0; r < 4; ++r) {
                atomicAdd(&fsum0[o * 16 + l4 * 4 + r], sums[r]);
                atomicAdd(&fsq0[o * 16 + l4 * 4 + r],  sqs[r]);
            }
        }
    }
}

// ---------------------------------------------------------------------------
// k_bn0_wo: transposed layout.  grid = (o 0..31, xc 0..7) = 256 blocks,
// 256 thr: xl = t&63, ug = t>>6 (wave-uniform).  Stage bn0-applied o1 tile
// [16 j][64 xl] in LDS (coalesced reads), per-thread 4-u Wo matmul + relu
// residual, in-place write, wave-reduced BN1 stat atomics.
// ---------------------------------------------------------------------------
__global__ __launch_bounds__(256) void k_bn0_wo(
    float* __restrict__ OpreT,
    const float* __restrict__ fsum0, const float* __restrict__ fsq0,
    const float* __restrict__ g0,    const float* __restrict__ beta0,
    const float* __restrict__ Wo,    const float* __restrict__ bo,
    float* __restrict__ fsum1,       float* __restrict__ fsq1)
{
    __shared__ float sh[16][64];
    const int o = blockIdx.x >> 3, xc = blockIdx.x & 7;
    const int x0 = xc * 64;
    const int t = threadIdx.x;
    const int xl = t & 63, ug = t >> 6;

#pragma unroll
    for (int k = 0; k < 4; ++k) {
        int j = k * 4 + ug;
        int f = o * 16 + j;
        float mean = fsum0[f] * (1.f / X_);
        float var  = fsq0[f] * (1.f / X_) - mean * mean;
        float rstd = rsqrtf(var + 1e-5f);
        float val = OpreT[(size_t)f * X_ + x0 + xl];
        sh[j][xl] = g0[f] * (val - mean) * rstd + beta0[f];
    }
    __syncthreads();

    float accv[4];
#pragma unroll
    for (int r = 0; r < 4; ++r) accv[r] = bo[ug * 4 + r];
#pragma unroll
    for (int j = 0; j < 16; ++j) {
        float sj = sh[j][xl];
#pragma unroll
        for (int r = 0; r < 4; ++r)
            accv[r] = fmaf(Wo[(ug * 4 + r) * 16 + j], sj, accv[r]);
    }
    float sums[4], sqs[4];
#pragma unroll
    for (int r = 0; r < 4; ++r) {
        float o1 = sh[ug * 4 + r][xl];
        float rr = o1 + fmaxf(accv[r], 0.f);
        OpreT[(size_t)(o * 16 + ug * 4 + r) * X_ + x0 + xl] = rr;
        sums[r] = rr; sqs[r] = rr * rr;
    }
#pragma unroll
    for (int mm = 1; mm < 64; mm <<= 1) {
#pragma unroll
        for (int r = 0; r < 4; ++r) {
            sums[r] += __shfl_xor(sums[r], mm, 64);
            sqs[r]  += __shfl_xor(sqs[r], mm, 64);
        }
    }
    if (xl == 0) {
#pragma unroll
        for (int r = 0; r < 4; ++r) {
            atomicAdd(&fsum1[o * 16 + ug * 4 + r], sums[r]);
            atomicAdd(&fsq1[o * 16 + ug * 4 + r],  sqs[r]);
        }
    }
}

// ---------------------------------------------------------------------------
// k_bn1_out: apply BN1; OpreT[f][x] -> out[bi][f][w] is coalesced f32x4 on
// both sides (out flat = (bi*512+f)*64 + w;  x = bi*64+w).
// ---------------------------------------------------------------------------
__global__ __launch_bounds__(256) void k_bn1_out(
    const float* __restrict__ OpreT,
    const float* __restrict__ fsum1, const float* __restrict__ fsq1,
    const float* __restrict__ g1,    const float* __restrict__ beta1,
    f32x4* __restrict__ out4)
{
    const int idx = blockIdx.x * 256 + threadIdx.x;   // 65536 vec4s
    const int w4 = idx & 15;
    const int f  = (idx >> 4) & 511;
    const int bi = idx >> 13;

    const float mean = fsum1[f] * (1.f / X_);
    const float var  = fsq1[f] * (1.f / X_) - mean * mean;
    const float rstd = rsqrtf(var + 1e-5f);
    const float g = g1[f], be = beta1[f];

    f32x4 v = *(const f32x4*)&OpreT[(size_t)f * X_ + bi * 64 + w4 * 4];
    f32x4 r;
#pragma unroll
    for (int e = 0; e < 4; ++e) r[e] = g * (v[e] - mean) * rstd + be;
    out4[idx] = r;
}

// ---------------------------------------------------------------------------
extern "C" void kernel_launch(void* const* d_in, const int* in_sizes, int n_in,
                              void* d_out, int out_size, void* d_ws, size_t ws_size,
                              hipStream_t stream)
{
    const float* Xin = (const float*)d_in[0];
    const float* Wc  = (const float*)d_in[1];
    const float* M   = (const float*)d_in[2];
    const float* S   = (const float*)d_in[3];
    // d_in[4] = p_logit: constant in n, cancels in the softmax — unused.
    const float* Wk  = (const float*)d_in[5];
    const float* bk  = (const float*)d_in[6];
    const float* Wv  = (const float*)d_in[7];
    const float* bv  = (const float*)d_in[8];
    const float* Wo  = (const float*)d_in[9];
    const float* bo  = (const float*)d_in[10];
    const float* g0  = (const float*)d_in[11];
    const float* b0  = (const float*)d_in[12];
    const float* g1  = (const float*)d_in[13];
    const float* b1  = (const float*)d_in[14];
    float* out = (float*)d_out;

    // ---- workspace: 1.35 MB total (round-4 proved >=2.1 MB safe) ----
    char* base = (char*)d_ws;
    _Float16* Wc16T = (_Float16*)base;                 // 294,912 B
    float* stats = (float*)(base + 294912);            // 8,192 B
    float* fsum0 = stats;
    float* fsq0  = fsum0 + 512;
    float* fsum1 = fsq0  + 512;
    float* fsq1  = fsum1 + 512;
    float* OpreT = stats + 2048;                       // 1 MB, [512 f][512 x]

    prep     <<<577, 256, 0, stream>>>(Wc, Wc16T, stats);
    k1_mfma  <<<1024, 256, 0, stream>>>(Xin, Wc16T, M, S, Wk, bk, Wv, bv,
                                        OpreT, fsum0, fsq0);
    k_bn0_wo <<<256, 256, 0, stream>>>(OpreT, fsum0, fsq0, g0, b0, Wo, bo,
                                       fsum1, fsq1);
    k_bn1_out<<<256, 256, 0, stream>>>(OpreT, fsum1, fsq1, g1, b1, (f32x4*)out);
}